// Round 15
// baseline (275.855 us; speedup 1.0000x reference)
//
#include <hip/hip_runtime.h>
#include <hip/hip_bf16.h>
#include <hip/hip_fp16.h>
#include <float.h>

// Model constants: N=20000, E=320000, F_IN=256, HID=32, HEADS=8, EDGE_DIM=8
// Edge record (32 B): [0] src:int, [4..20) aed1: 8 x f16, [20] aed2: f32, pad.

typedef short v8s __attribute__((ext_vector_type(8)));
typedef float v4f __attribute__((ext_vector_type(4)));

#define WSYNC() do { __asm__ volatile("" ::: "memory"); __builtin_amdgcn_wave_barrier(); } while (0)

__device__ __forceinline__ ushort f2bf(float f) {
  unsigned u = __float_as_uint(f);
  u = (u + 0x7FFF + ((u >> 16) & 1)) >> 16;
  return (ushort)u;
}
__device__ __forceinline__ float bf2f(ushort h) {
  return __uint_as_float(((unsigned)h) << 16);
}
__device__ __forceinline__ unsigned pk2bf(float lo, float hi) {
  return (unsigned)f2bf(lo) | ((unsigned)f2bf(hi) << 16);
}
__device__ __forceinline__ unsigned pk2h(float lo, float hi) {
  return (unsigned)__half_as_ushort(__float2half(lo)) |
         ((unsigned)__half_as_ushort(__float2half(hi)) << 16);
}

// ---- k_pre: deg count + W1 transpose + M1/m2 prep + W2 blocked transpose
__global__ __launch_bounds__(256) void k_pre(const int* __restrict__ dst,
                                             const float* __restrict__ W1,
                                             const float* __restrict__ We1,
                                             const float* __restrict__ ae1,
                                             const float* __restrict__ We2,
                                             const float* __restrict__ ae2,
                                             const float* __restrict__ W2,
                                             int* __restrict__ deg,
                                             ushort* __restrict__ Bt,
                                             float* __restrict__ M1,
                                             float* __restrict__ m2,
                                             float* __restrict__ W2B,
                                             int E, int DB) {
  int b = blockIdx.x;
  if (b < DB) {
    int e = b * 256 + threadIdx.x;
    if (e < E) atomicAdd(&deg[dst[e]], 1);
    return;
  }
  if (b == DB + 64) {
    int t = threadIdx.x;
    for (int i = t; i < 8192; i += 256) {
      int k = i >> 5, cc = i & 31;
      W2B[(size_t)(k >> 2) * 128 + cc * 4 + (k & 3)] = W2[(size_t)k * 32 + cc];
    }
    if (t < 64) {
      int k = t >> 3, h = t & 7;
      float s = 0.f;
      for (int c = 0; c < 32; c++) s += We1[k * 256 + h * 32 + c] * ae1[h * 32 + c];
      M1[k * 8 + h] = s;
    } else if (t < 72) {
      int k = t - 64;
      float s = 0.f;
      for (int c = 0; c < 32; c++) s += We2[k * 32 + c] * ae2[c];
      m2[k] = s;
    }
    return;
  }
  int b2 = b - DB;
  __shared__ float tile[32][33];
  int bx = b2 & 7, by = b2 >> 3;
  int tx = threadIdx.x & 31, ty = threadIdx.x >> 5;
  for (int r = ty; r < 32; r += 8)
    tile[r][tx] = W1[(size_t)(by * 32 + r) * 256 + bx * 32 + tx];
  __syncthreads();
  for (int r = ty; r < 32; r += 8)
    Bt[(size_t)(bx * 32 + r) * 256 + by * 32 + tx] = f2bf(tile[tx][r]);
}

// ---------------------------------------------------------------- CSR build
__global__ __launch_bounds__(1024) void k_scan(const int* __restrict__ deg,
                                               int* __restrict__ row_ptr,
                                               int* __restrict__ cursor, int N) {
  __shared__ int part[1024];
  int tid = threadIdx.x;
  int chunk = (N + 1023) / 1024;
  int lo = tid * chunk;
  if (lo > N) lo = N;
  int hi = lo + chunk;
  if (hi > N) hi = N;
  int s = 0;
  for (int i = lo; i < hi; i++) { s += deg[i]; cursor[i] = 0; }
  part[tid] = s;
  __syncthreads();
  for (int off = 1; off < 1024; off <<= 1) {
    int v = 0;
    if (tid >= off) v = part[tid - off];
    __syncthreads();
    part[tid] += v;
    __syncthreads();
  }
  int base = part[tid] - s;  // exclusive prefix
  for (int i = lo; i < hi; i++) { row_ptr[i] = base; base += deg[i]; }
  if (tid == 1023) row_ptr[N] = part[1023];
}

// ---- k_mega1: blocks [0,GB) = MFMA gemm1 (+fused attn1); [GB,GB+DB) = scatter.
__global__ __launch_bounds__(256) void k_mega1(
    const float* __restrict__ A, const ushort* __restrict__ Bt,
    const float* __restrict__ as1, const float* __restrict__ ad1,
    ushort* __restrict__ h1b, float* __restrict__ asv, float* __restrict__ adv, int M,
    const int* __restrict__ src, const int* __restrict__ dst,
    const float* __restrict__ ea, const float* __restrict__ Wse,
    const float* __restrict__ bse, const float* __restrict__ M1,
    const float* __restrict__ m2, const int* __restrict__ row_ptr,
    int* __restrict__ cursor, char* __restrict__ rec, int E, int GB) {
  __shared__ __align__(16) char smem[27648];
  int t = threadIdx.x;
  if (blockIdx.x >= GB) {
    float* sW  = (float*)smem;
    float* sbv = sW + 16;
    float* sM  = sbv + 8;
    float* sm2 = sM + 64;
    if (t < 16) sW[t] = Wse[t];
    if (t < 8) sbv[t] = bse[t];
    if (t < 64) sM[t] = M1[t];
    if (t >= 64 && t < 72) sm2[t - 64] = m2[t - 64];
    __syncthreads();
    int i = (blockIdx.x - GB) * 256 + t;
    if (i >= E) return;
    float2 av = ((const float2*)ea)[i];
    float e8[8];
#pragma unroll
    for (int k = 0; k < 8; k++)
      e8[k] = fmaxf(av.x * sW[k] + av.y * sW[8 + k] + sbv[k], 0.f);
    float o[8];
#pragma unroll
    for (int h = 0; h < 8; h++) {
      float s = 0.f;
#pragma unroll
      for (int k = 0; k < 8; k++) s += e8[k] * sM[k * 8 + h];
      o[h] = s;
    }
    float s2 = 0.f;
#pragma unroll
    for (int k = 0; k < 8; k++) s2 += e8[k] * sm2[k];
    int d = dst[i];
    int pos = row_ptr[d] + atomicAdd(&cursor[d], 1);
    uint4 w0, w1;
    w0.x = (unsigned)src[i];
    w0.y = pk2h(o[0], o[1]);
    w0.z = pk2h(o[2], o[3]);
    w0.w = pk2h(o[4], o[5]);
    w1.x = pk2h(o[6], o[7]);
    w1.y = __float_as_uint(s2);
    w1.z = 0; w1.w = 0;
    *(uint4*)(rec + (size_t)pos * 32)      = w0;
    *(uint4*)(rec + (size_t)pos * 32 + 16) = w1;
    return;
  }
  // gemm1 path
  ushort* sA = (ushort*)smem;
  ushort* sB = (ushort*)(smem + 5120);
  float* sas = (float*)(smem + 25600);
  float* sad = (float*)(smem + 26624);
  int wave = t >> 6, lane = t & 63;
  int m0 = blockIdx.x * 64;
  int c = lane & 15, kg = lane >> 4;
  sas[t] = as1[t];
  sad[t] = ad1[t];
  v4f acc[4][4];
#pragma unroll
  for (int a = 0; a < 4; a++)
#pragma unroll
    for (int b = 0; b < 4; b++) acc[a][b] = (v4f)(0.f);
  int arow = t >> 2;
  int akoff = (t & 3) * 8;
  bool aval = (m0 + arow) < M;
  const float* aptr = A + (size_t)(m0 + arow) * 256 + akoff;
  const ushort* bptr = Bt + (size_t)t * 256;
  for (int k0 = 0; k0 < 256; k0 += 32) {
    float4 v0 = make_float4(0.f, 0.f, 0.f, 0.f), v1 = v0;
    if (aval) { v0 = *(const float4*)(aptr + k0); v1 = *(const float4*)(aptr + k0 + 4); }
    unsigned* dst32 = (unsigned*)&sA[arow * 40 + akoff];
    dst32[0] = pk2bf(v0.x, v0.y);
    dst32[1] = pk2bf(v0.z, v0.w);
    dst32[2] = pk2bf(v1.x, v1.y);
    dst32[3] = pk2bf(v1.z, v1.w);
    *(v8s*)&sB[t * 40 + 0]  = *(const v8s*)(bptr + k0 + 0);
    *(v8s*)&sB[t * 40 + 8]  = *(const v8s*)(bptr + k0 + 8);
    *(v8s*)&sB[t * 40 + 16] = *(const v8s*)(bptr + k0 + 16);
    *(v8s*)&sB[t * 40 + 24] = *(const v8s*)(bptr + k0 + 24);
    __syncthreads();
    v8s af[4], bfr[4];
#pragma unroll
    for (int mt = 0; mt < 4; mt++) af[mt] = *(v8s*)&sA[(mt * 16 + c) * 40 + kg * 8];
#pragma unroll
    for (int nt = 0; nt < 4; nt++) bfr[nt] = *(v8s*)&sB[(wave * 64 + nt * 16 + c) * 40 + kg * 8];
#pragma unroll
    for (int mt = 0; mt < 4; mt++)
#pragma unroll
      for (int nt = 0; nt < 4; nt++)
        acc[mt][nt] = __builtin_amdgcn_mfma_f32_16x16x32_bf16(af[mt], bfr[nt], acc[mt][nt], 0, 0, 0);
    __syncthreads();
  }
  int colbase = wave * 64;
#pragma unroll
  for (int mt = 0; mt < 4; mt++) {
#pragma unroll
    for (int i = 0; i < 4; i++) {
      int m = m0 + mt * 16 + kg * 4 + i;
      if (m < M) {
#pragma unroll
        for (int nt = 0; nt < 4; nt++)
          h1b[(size_t)m * 256 + colbase + nt * 16 + c] = f2bf(acc[mt][nt][i]);
      }
      float s1a = acc[mt][0][i] * sas[colbase + c]      + acc[mt][1][i] * sas[colbase + 16 + c];
      float s2a = acc[mt][0][i] * sad[colbase + c]      + acc[mt][1][i] * sad[colbase + 16 + c];
      float s1b = acc[mt][2][i] * sas[colbase + 32 + c] + acc[mt][3][i] * sas[colbase + 48 + c];
      float s2b = acc[mt][2][i] * sad[colbase + 32 + c] + acc[mt][3][i] * sad[colbase + 48 + c];
#pragma unroll
      for (int o = 1; o < 16; o <<= 1) {
        s1a += __shfl_xor(s1a, o);
        s2a += __shfl_xor(s2a, o);
        s1b += __shfl_xor(s1b, o);
        s2b += __shfl_xor(s2b, o);
      }
      if (c == 0 && m < M) {
        asv[(size_t)m * 8 + 2 * wave]     = s1a;
        adv[(size_t)m * 8 + 2 * wave]     = s2a;
        asv[(size_t)m * 8 + 2 * wave + 1] = s1b;
        adv[(size_t)m * 8 + 2 * wave + 1] = s2b;
      }
    }
  }
}

// ---- conv1: 4 independent waves/block; softmax state + weights in REGISTERS
// (shuffles, all lanes active at every shuffle); LDS only for gemm2 staging.
// Lane roles: logit phase owns (el = j*8 + (lane>>3), head = lane&7), j=0..7;
// accumulate phase owns 4 channels of head h = lane>>3.
__global__ __launch_bounds__(256) void k_conv1(
    const int* __restrict__ row_ptr, const char* __restrict__ rec,
    const float* __restrict__ asv, const float* __restrict__ adv,
    const ushort* __restrict__ h1b, const float* __restrict__ b1,
    const float* __restrict__ W2B, const float* __restrict__ as2,
    const float* __restrict__ ad2, float* __restrict__ g2,
    float* __restrict__ asv2, float* __restrict__ adv2, int N) {
  __shared__ float sh2_all[4][256];
  int wid = threadIdx.x >> 6;
  int lane = threadIdx.x & 63;
  int n = blockIdx.x * 4 + wid;
  if (n >= N) return;  // whole-wave exit; no block barriers anywhere
  float* sh2 = sh2_all[wid];
  int h = lane >> 3;     // accumulate head
  int rgrp = lane >> 3;  // logit el-group
  int hh = lane & 7;     // logit head
  int begin = row_ptr[n], end = row_ptr[n + 1];
  int degr = end - begin;
  float advn = adv[(size_t)n * 8 + hh];
  float m_run = -FLT_MAX, l_run = 0.f, aedsum = 0.f;
  float4 acc = make_float4(0.f, 0.f, 0.f, 0.f);
  for (int cs = begin; cs < end; cs += 64) {
    int c = min(64, end - cs);
    int srcid = 0;
    if (lane < c) srcid = *(const int*)(rec + (size_t)(cs + lane) * 32);
    // logits in registers
    float wreg[8];
    float mloc = -FLT_MAX;
#pragma unroll
    for (int j = 0; j < 8; j++) {
      int el = j * 8 + rgrp;
      int se = __shfl(srcid, el);  // all lanes active; garbage only if el>=c (unused)
      float a = -FLT_MAX;
      if (el < c) {
        float ae = __half2float(*(const __half*)(rec + (size_t)(cs + el) * 32 + 4 + hh * 2));
        aedsum += ae;
        a = asv[(size_t)se * 8 + hh] + advn + ae;
        a = a > 0.f ? a : 0.2f * a;
      }
      wreg[j] = a;
      mloc = fmaxf(mloc, a);
    }
    mloc = fmaxf(mloc, __shfl_xor(mloc, 8));
    mloc = fmaxf(mloc, __shfl_xor(mloc, 16));
    mloc = fmaxf(mloc, __shfl_xor(mloc, 32));
    float mnew = fmaxf(m_run, mloc);
    float scale = __expf(m_run - mnew);
    float lloc = 0.f;
#pragma unroll
    for (int j = 0; j < 8; j++) {
      int el = j * 8 + rgrp;
      float w = (el < c) ? __expf(wreg[j] - mnew) : 0.f;
      wreg[j] = w;
      lloc += w;
    }
    lloc += __shfl_xor(lloc, 8);
    lloc += __shfl_xor(lloc, 16);
    lloc += __shfl_xor(lloc, 32);
    l_run = l_run * scale + lloc;
    m_run = mnew;
    float sc_h = __shfl(scale, h);  // lane h holds head-h scale (lane<8 => hh==h)
    acc.x *= sc_h; acc.y *= sc_h; acc.z *= sc_h; acc.w *= sc_h;
    // accumulate: uniform guards; weight at lane (e8*8 + h), register j
#pragma unroll
    for (int j = 0; j < 8; j++) {
#pragma unroll
      for (int e8 = 0; e8 < 8; e8++) {
        int el = j * 8 + e8;
        if (el < c) {  // runtime-uniform
          int se = __shfl(srcid, el);
          float w = __shfl(wreg[j], (e8 << 3) | h);
          ushort4 hv = *(const ushort4*)(h1b + (size_t)se * 256 + lane * 4);
          acc.x += w * bf2f(hv.x);
          acc.y += w * bf2f(hv.y);
          acc.z += w * bf2f(hv.z);
          acc.w += w * bf2f(hv.w);
        }
      }
    }
  }
  // per-head aed totals (head hh at every lane), then pick head h's values
  aedsum += __shfl_xor(aedsum, 8);
  aedsum += __shfl_xor(aedsum, 16);
  aedsum += __shfl_xor(aedsum, 32);
  float invd = 1.f / (float)(degr > 1 ? degr : 1);
  float mean_h = __shfl(aedsum, h) * invd;
  float m_h = __shfl(m_run, h);
  float l_h = __shfl(l_run, h);
  // merged self-loop step (everything per accumulate-head h)
  float a_self = asv[(size_t)n * 8 + h] + adv[(size_t)n * 8 + h] + mean_h;
  a_self = a_self > 0.f ? a_self : 0.2f * a_self;
  float mnew = fmaxf(m_h, a_self);
  float scale = __expf(m_h - mnew);
  float w_self = __expf(a_self - mnew);
  float l_fin = l_h * scale + w_self;
  ushort4 hs = *(const ushort4*)(h1b + (size_t)n * 256 + lane * 4);
  acc.x = acc.x * scale + w_self * bf2f(hs.x);
  acc.y = acc.y * scale + w_self * bf2f(hs.y);
  acc.z = acc.z * scale + w_self * bf2f(hs.z);
  acc.w = acc.w * scale + w_self * bf2f(hs.w);
  float inv = 1.f / (l_fin + 1e-16f);
  float4 bv = *(const float4*)(b1 + lane * 4);
  float4 h2v;
  h2v.x = fmaxf(acc.x * inv + bv.x, 0.f);
  h2v.y = fmaxf(acc.y * inv + bv.y, 0.f);
  h2v.z = fmaxf(acc.z * inv + bv.z, 0.f);
  h2v.w = fmaxf(acc.w * inv + bv.w, 0.f);
  *(float4*)&sh2[lane * 4] = h2v;
  WSYNC();
  // fused gemm2: g2[cc] = sum_k h2[k] * W2[k][cc]; halves split k-range.
  int half = lane >> 5, cc = lane & 31;
  const float* wp = W2B + (size_t)half * 32 * 128 + cc * 4;
  const float* hp2 = sh2 + half * 128;
  float part = 0.f;
#pragma unroll 8
  for (int g = 0; g < 32; g++) {
    float4 wv = *(const float4*)(wp + g * 128);
    float4 hv = *(const float4*)(hp2 + g * 4);
    part += wv.x * hv.x + wv.y * hv.y + wv.z * hv.z + wv.w * hv.w;
  }
  part += __shfl_xor(part, 32);
  float s1 = part * as2[cc];
  float s2 = part * ad2[cc];
#pragma unroll
  for (int o = 1; o < 32; o <<= 1) {
    s1 += __shfl_xor(s1, o);
    s2 += __shfl_xor(s2, o);
  }
  if (lane < 32) g2[(size_t)n * 32 + cc] = part;
  if (lane == 0) { asv2[n] = s1; adv2[n] = s2; }
}

// ---- conv2: 4 independent waves/block, zero LDS; weights/src via shuffles
// with uniform trip counts (shuffles before the per-lane guard).
__global__ __launch_bounds__(256) void k_conv2(
    const int* __restrict__ row_ptr, const char* __restrict__ rec,
    const float* __restrict__ asv2, const float* __restrict__ adv2,
    const float* __restrict__ g2, const float* __restrict__ b2,
    float* __restrict__ out, int N) {
  int wid = threadIdx.x >> 6;
  int lane = threadIdx.x & 63;
  int n = blockIdx.x * 4 + wid;
  if (n >= N) return;
  int sub = lane >> 3, q = lane & 7;
  int begin = row_ptr[n], end = row_ptr[n + 1];
  int degr = end - begin;
  float advn = adv2[n];
  float m = -FLT_MAX, l = 0.f, aedsum = 0.f;
  float4 acc = make_float4(0.f, 0.f, 0.f, 0.f);
  for (int cs = begin; cs < end; cs += 64) {
    int c = min(64, end - cs);
    int srcid = 0;
    float a = -FLT_MAX;
    if (lane < c) {
      const char* rp = rec + (size_t)(cs + lane) * 32;
      srcid = *(const int*)rp;
      float ae = *(const float*)(rp + 20);
      aedsum += ae;
      a = asv2[srcid] + advn + ae;
      a = a > 0.f ? a : 0.2f * a;
    }
    float cm = a;
#pragma unroll
    for (int o = 1; o < 64; o <<= 1) cm = fmaxf(cm, __shfl_xor(cm, o));
    float nm = fmaxf(m, cm);
    float sc = __expf(m - nm);
    float w = (lane < c) ? __expf(a - nm) : 0.f;
    float cl = w;
#pragma unroll
    for (int o = 1; o < 64; o <<= 1) cl += __shfl_xor(cl, o);
    l = l * sc + cl;
    m = nm;
    acc.x *= sc; acc.y *= sc; acc.z *= sc; acc.w *= sc;
    int kmax = (c + 7) >> 3;  // uniform trip count
    for (int k = 0; k < kmax; k++) {
      int el = k * 8 + sub;   // <= 63 always
      float w2 = __shfl(w, el);     // all lanes active
      int se = __shfl(srcid, el);
      if (el < c) {
        const float4 gv = *(const float4*)(g2 + (size_t)se * 32 + q * 4);
        acc.x += w2 * gv.x; acc.y += w2 * gv.y; acc.z += w2 * gv.z; acc.w += w2 * gv.w;
      }
    }
  }
  // self-loop merge
#pragma unroll
  for (int o = 1; o < 64; o <<= 1) aedsum += __shfl_xor(aedsum, o);
  float invd = 1.f / (float)(degr > 1 ? degr : 1);
  float a_self = asv2[n] + advn + aedsum * invd;
  a_self = a_self > 0.f ? a_self : 0.2f * a_self;
  float nm = fmaxf(m, a_self);
  float sc = __expf(m - nm);
  float w_self = __expf(a_self - nm);
  l = l * sc + w_self;
  acc.x *= sc; acc.y *= sc; acc.z *= sc; acc.w *= sc;
  if (sub == 0) {
    const float4 gv = *(const float4*)(g2 + (size_t)n * 32 + q * 4);
    acc.x += w_self * gv.x; acc.y += w_self * gv.y;
    acc.z += w_self * gv.z; acc.w += w_self * gv.w;
  }
#pragma unroll
  for (int o = 8; o < 64; o <<= 1) {
    acc.x += __shfl_xor(acc.x, o);
    acc.y += __shfl_xor(acc.y, o);
    acc.z += __shfl_xor(acc.z, o);
    acc.w += __shfl_xor(acc.w, o);
  }
  if (lane < 8) {
    float inv = 1.f / (l + 1e-16f);
    float4 bv = *(const float4*)(b2 + lane * 4);
    float4 o4;
    o4.x = acc.x * inv + bv.x;
    o4.y = acc.y * inv + bv.y;
    o4.z = acc.z * inv + bv.z;
    o4.w = acc.w * inv + bv.w;
    *(float4*)(out + (size_t)n * 32 + lane * 4) = o4;
  }
}

// ---------------------------------------------------------------- launch
extern "C" void kernel_launch(void* const* d_in, const int* in_sizes, int n_in,
                              void* d_out, int out_size, void* d_ws, size_t ws_size,
                              hipStream_t stream) {
  (void)n_in; (void)out_size; (void)ws_size;
  const float* x   = (const float*)d_in[0];
  const int*   ei  = (const int*)d_in[1];
  const float* ea  = (const float*)d_in[2];
  const float* Wse = (const float*)d_in[3];
  const float* bse = (const float*)d_in[4];
  const float* W1  = (const float*)d_in[5];
  const float* as1 = (const float*)d_in[6];
  const float* ad1 = (const float*)d_in[7];
  const float* We1 = (const float*)d_in[8];
  const float* ae1 = (const float*)d_in[9];
  const float* b1  = (const float*)d_in[10];
  const float* W2  = (const float*)d_in[11];
  const float* as2 = (const float*)d_in[12];
  const float* ad2 = (const float*)d_in[13];
  const float* We2 = (const float*)d_in[14];
  const float* ae2 = (const float*)d_in[15];
  const float* b2  = (const float*)d_in[16];
  const int N = in_sizes[0] / 256;
  const int E = in_sizes[1] / 2;
  const int* src = ei;
  const int* dst = ei + E;

  char* base = (char*)d_ws;
  size_t off = 0;
  auto alloc = [&](size_t bytes) -> char* {
    off = (off + 255) & ~(size_t)255;
    char* p = base + off;
    off += bytes;
    return p;
  };
  int*   deg      = (int*)alloc((size_t)N * 4);
  int*   cursor   = (int*)alloc((size_t)N * 4);
  int* row_ptr    = (int*)alloc((size_t)(N + 1) * 4);
  char* rec       = alloc((size_t)E * 32);
  ushort* W1T     = (ushort*)alloc((size_t)256 * 256 * 2);
  float* W2B      = (float*)alloc((size_t)256 * 32 * 4);
  ushort* h1b     = (ushort*)alloc((size_t)N * 256 * 2);
  float* asv1     = (float*)alloc((size_t)N * 8 * 4);
  float* adv1     = (float*)alloc((size_t)N * 8 * 4);
  float* g2       = (float*)alloc((size_t)N * 32 * 4);
  float* asv2     = (float*)alloc((size_t)N * 4);
  float* adv2     = (float*)alloc((size_t)N * 4);
  float* M1       = (float*)alloc(64 * 4);
  float* m2       = (float*)alloc(8 * 4);

  const int DB = (E + 255) / 256;
  const int GB = (N + 63) / 64;
  hipMemsetAsync(deg, 0, (size_t)N * 4, stream);
  k_pre<<<DB + 65, 256, 0, stream>>>(dst, W1, We1, ae1, We2, ae2, W2,
                                     deg, W1T, M1, m2, W2B, E, DB);
  k_scan<<<1, 1024, 0, stream>>>(deg, row_ptr, cursor, N);
  k_mega1<<<GB + DB, 256, 0, stream>>>(x, W1T, as1, ad1, h1b, asv1, adv1, N,
                                       src, dst, ea, Wse, bse, M1, m2, row_ptr,
                                       cursor, rec, E, GB);
  k_conv1<<<(N + 3) / 4, 256, 0, stream>>>(row_ptr, rec, asv1, adv1, h1b, b1,
                                           W2B, as2, ad2, g2, asv2, adv2, N);
  k_conv2<<<(N + 3) / 4, 256, 0, stream>>>(row_ptr, rec, asv2, adv2, g2, b2,
                                           (float*)d_out, N);
}

// Round 16
// 228.290 us; speedup vs baseline: 1.2084x; 1.2084x over previous
//
#include <hip/hip_runtime.h>
#include <hip/hip_bf16.h>
#include <hip/hip_fp16.h>
#include <float.h>

// Model constants: N=20000, E=320000, F_IN=256, HID=32, HEADS=8, EDGE_DIM=8
// Edge record (32 B): [0] src:int, [4..20) aed1: 8 x f16, [20] aed2: f32, pad.

typedef short v8s __attribute__((ext_vector_type(8)));
typedef float v4f __attribute__((ext_vector_type(4)));

__device__ __forceinline__ ushort f2bf(float f) {
  unsigned u = __float_as_uint(f);
  u = (u + 0x7FFF + ((u >> 16) & 1)) >> 16;
  return (ushort)u;
}
__device__ __forceinline__ float bf2f(ushort h) {
  return __uint_as_float(((unsigned)h) << 16);
}
__device__ __forceinline__ unsigned pk2bf(float lo, float hi) {
  return (unsigned)f2bf(lo) | ((unsigned)f2bf(hi) << 16);
}
__device__ __forceinline__ unsigned pk2h(float lo, float hi) {
  return (unsigned)__half_as_ushort(__float2half(lo)) |
         ((unsigned)__half_as_ushort(__float2half(hi)) << 16);
}

// ---- k_pre: deg count + W1 transpose + M1/m2 prep + W2 blocked transpose (bf16)
__global__ __launch_bounds__(256) void k_pre(const int* __restrict__ dst,
                                             const float* __restrict__ W1,
                                             const float* __restrict__ We1,
                                             const float* __restrict__ ae1,
                                             const float* __restrict__ We2,
                                             const float* __restrict__ ae2,
                                             const float* __restrict__ W2,
                                             int* __restrict__ deg,
                                             ushort* __restrict__ Bt,
                                             float* __restrict__ M1,
                                             float* __restrict__ m2,
                                             ushort* __restrict__ W2B,
                                             int E, int DB) {
  int b = blockIdx.x;
  if (b < DB) {
    int e = b * 256 + threadIdx.x;
    if (e < E) atomicAdd(&deg[dst[e]], 1);
    return;
  }
  if (b == DB + 64) {
    int t = threadIdx.x;
    // W2B[(k>>2)*128 + cc*4 + (k&3)] = bf16(W2[k][cc])
    for (int i = t; i < 8192; i += 256) {
      int k = i >> 5, cc = i & 31;
      W2B[(size_t)(k >> 2) * 128 + cc * 4 + (k & 3)] = f2bf(W2[(size_t)k * 32 + cc]);
    }
    if (t < 64) {
      int k = t >> 3, h = t & 7;
      float s = 0.f;
      for (int c = 0; c < 32; c++) s += We1[k * 256 + h * 32 + c] * ae1[h * 32 + c];
      M1[k * 8 + h] = s;
    } else if (t < 72) {
      int k = t - 64;
      float s = 0.f;
      for (int c = 0; c < 32; c++) s += We2[k * 32 + c] * ae2[c];
      m2[k] = s;
    }
    return;
  }
  int b2 = b - DB;
  __shared__ float tile[32][33];
  int bx = b2 & 7, by = b2 >> 3;
  int tx = threadIdx.x & 31, ty = threadIdx.x >> 5;
  for (int r = ty; r < 32; r += 8)
    tile[r][tx] = W1[(size_t)(by * 32 + r) * 256 + bx * 32 + tx];
  __syncthreads();
  for (int r = ty; r < 32; r += 8)
    Bt[(size_t)(bx * 32 + r) * 256 + by * 32 + tx] = f2bf(tile[tx][r]);
}

// ---------------------------------------------------------------- CSR build
__global__ __launch_bounds__(1024) void k_scan(const int* __restrict__ deg,
                                               int* __restrict__ row_ptr,
                                               int* __restrict__ cursor, int N) {
  __shared__ int part[1024];
  int tid = threadIdx.x;
  int chunk = (N + 1023) / 1024;
  int lo = tid * chunk;
  if (lo > N) lo = N;
  int hi = lo + chunk;
  if (hi > N) hi = N;
  int s = 0;
  for (int i = lo; i < hi; i++) { s += deg[i]; cursor[i] = 0; }
  part[tid] = s;
  __syncthreads();
  for (int off = 1; off < 1024; off <<= 1) {
    int v = 0;
    if (tid >= off) v = part[tid - off];
    __syncthreads();
    part[tid] += v;
    __syncthreads();
  }
  int base = part[tid] - s;  // exclusive prefix
  for (int i = lo; i < hi; i++) { row_ptr[i] = base; base += deg[i]; }
  if (tid == 1023) row_ptr[N] = part[1023];
}

// ---- k_mega1: blocks [0,GB) = MFMA gemm1 (+fused attn1); [GB,GB+DB) = scatter.
__global__ __launch_bounds__(256) void k_mega1(
    const float* __restrict__ A, const ushort* __restrict__ Bt,
    const float* __restrict__ as1, const float* __restrict__ ad1,
    ushort* __restrict__ h1b, float* __restrict__ asv, float* __restrict__ adv, int M,
    const int* __restrict__ src, const int* __restrict__ dst,
    const float* __restrict__ ea, const float* __restrict__ Wse,
    const float* __restrict__ bse, const float* __restrict__ M1,
    const float* __restrict__ m2, const int* __restrict__ row_ptr,
    int* __restrict__ cursor, char* __restrict__ rec, int E, int GB) {
  __shared__ __align__(16) char smem[27648];
  int t = threadIdx.x;
  if (blockIdx.x >= GB) {
    float* sW  = (float*)smem;
    float* sbv = sW + 16;
    float* sM  = sbv + 8;
    float* sm2 = sM + 64;
    if (t < 16) sW[t] = Wse[t];
    if (t < 8) sbv[t] = bse[t];
    if (t < 64) sM[t] = M1[t];
    if (t >= 64 && t < 72) sm2[t - 64] = m2[t - 64];
    __syncthreads();
    int i = (blockIdx.x - GB) * 256 + t;
    if (i >= E) return;
    float2 av = ((const float2*)ea)[i];
    float e8[8];
#pragma unroll
    for (int k = 0; k < 8; k++)
      e8[k] = fmaxf(av.x * sW[k] + av.y * sW[8 + k] + sbv[k], 0.f);
    float o[8];
#pragma unroll
    for (int h = 0; h < 8; h++) {
      float s = 0.f;
#pragma unroll
      for (int k = 0; k < 8; k++) s += e8[k] * sM[k * 8 + h];
      o[h] = s;
    }
    float s2 = 0.f;
#pragma unroll
    for (int k = 0; k < 8; k++) s2 += e8[k] * sm2[k];
    int d = dst[i];
    int pos = row_ptr[d] + atomicAdd(&cursor[d], 1);
    uint4 w0, w1;
    w0.x = (unsigned)src[i];
    w0.y = pk2h(o[0], o[1]);
    w0.z = pk2h(o[2], o[3]);
    w0.w = pk2h(o[4], o[5]);
    w1.x = pk2h(o[6], o[7]);
    w1.y = __float_as_uint(s2);
    w1.z = 0; w1.w = 0;
    *(uint4*)(rec + (size_t)pos * 32)      = w0;
    *(uint4*)(rec + (size_t)pos * 32 + 16) = w1;
    return;
  }
  // gemm1 path
  ushort* sA = (ushort*)smem;
  ushort* sB = (ushort*)(smem + 5120);
  float* sas = (float*)(smem + 25600);
  float* sad = (float*)(smem + 26624);
  int wave = t >> 6, lane = t & 63;
  int m0 = blockIdx.x * 64;
  int c = lane & 15, kg = lane >> 4;
  sas[t] = as1[t];
  sad[t] = ad1[t];
  v4f acc[4][4];
#pragma unroll
  for (int a = 0; a < 4; a++)
#pragma unroll
    for (int b = 0; b < 4; b++) acc[a][b] = (v4f)(0.f);
  int arow = t >> 2;
  int akoff = (t & 3) * 8;
  bool aval = (m0 + arow) < M;
  const float* aptr = A + (size_t)(m0 + arow) * 256 + akoff;
  const ushort* bptr = Bt + (size_t)t * 256;
  for (int k0 = 0; k0 < 256; k0 += 32) {
    float4 v0 = make_float4(0.f, 0.f, 0.f, 0.f), v1 = v0;
    if (aval) { v0 = *(const float4*)(aptr + k0); v1 = *(const float4*)(aptr + k0 + 4); }
    unsigned* dst32 = (unsigned*)&sA[arow * 40 + akoff];
    dst32[0] = pk2bf(v0.x, v0.y);
    dst32[1] = pk2bf(v0.z, v0.w);
    dst32[2] = pk2bf(v1.x, v1.y);
    dst32[3] = pk2bf(v1.z, v1.w);
    *(v8s*)&sB[t * 40 + 0]  = *(const v8s*)(bptr + k0 + 0);
    *(v8s*)&sB[t * 40 + 8]  = *(const v8s*)(bptr + k0 + 8);
    *(v8s*)&sB[t * 40 + 16] = *(const v8s*)(bptr + k0 + 16);
    *(v8s*)&sB[t * 40 + 24] = *(const v8s*)(bptr + k0 + 24);
    __syncthreads();
    v8s af[4], bfr[4];
#pragma unroll
    for (int mt = 0; mt < 4; mt++) af[mt] = *(v8s*)&sA[(mt * 16 + c) * 40 + kg * 8];
#pragma unroll
    for (int nt = 0; nt < 4; nt++) bfr[nt] = *(v8s*)&sB[(wave * 64 + nt * 16 + c) * 40 + kg * 8];
#pragma unroll
    for (int mt = 0; mt < 4; mt++)
#pragma unroll
      for (int nt = 0; nt < 4; nt++)
        acc[mt][nt] = __builtin_amdgcn_mfma_f32_16x16x32_bf16(af[mt], bfr[nt], acc[mt][nt], 0, 0, 0);
    __syncthreads();
  }
  int colbase = wave * 64;
#pragma unroll
  for (int mt = 0; mt < 4; mt++) {
#pragma unroll
    for (int i = 0; i < 4; i++) {
      int m = m0 + mt * 16 + kg * 4 + i;
      if (m < M) {
#pragma unroll
        for (int nt = 0; nt < 4; nt++)
          h1b[(size_t)m * 256 + colbase + nt * 16 + c] = f2bf(acc[mt][nt][i]);
      }
      float s1a = acc[mt][0][i] * sas[colbase + c]      + acc[mt][1][i] * sas[colbase + 16 + c];
      float s2a = acc[mt][0][i] * sad[colbase + c]      + acc[mt][1][i] * sad[colbase + 16 + c];
      float s1b = acc[mt][2][i] * sas[colbase + 32 + c] + acc[mt][3][i] * sas[colbase + 48 + c];
      float s2b = acc[mt][2][i] * sad[colbase + 32 + c] + acc[mt][3][i] * sad[colbase + 48 + c];
#pragma unroll
      for (int o = 1; o < 16; o <<= 1) {
        s1a += __shfl_xor(s1a, o);
        s2a += __shfl_xor(s2a, o);
        s1b += __shfl_xor(s1b, o);
        s2b += __shfl_xor(s2b, o);
      }
      if (c == 0 && m < M) {
        asv[(size_t)m * 8 + 2 * wave]     = s1a;
        adv[(size_t)m * 8 + 2 * wave]     = s2a;
        asv[(size_t)m * 8 + 2 * wave + 1] = s1b;
        adv[(size_t)m * 8 + 2 * wave + 1] = s2b;
      }
    }
  }
}

// ---- conv1: ONE WAVE per node (r11 structure); fused gemm2 epilogue with
// bf16 W2B (halves per-node weight traffic); g2 stored bf16.
__global__ __launch_bounds__(64) void k_conv1(
    const int* __restrict__ row_ptr, const char* __restrict__ rec,
    const float* __restrict__ asv, const float* __restrict__ adv,
    const ushort* __restrict__ h1b, const float* __restrict__ b1,
    const ushort* __restrict__ W2B, const float* __restrict__ as2,
    const float* __restrict__ ad2, ushort* __restrict__ g2b,
    float* __restrict__ asv2, float* __restrict__ adv2, int N) {
  int n = blockIdx.x;
  int lane = threadIdx.x;
  int h = lane >> 3;       // head owned in accumulate phase
  int sub = lane & 7;
  int hh = lane & 7;       // head owned in logit phase
  __shared__ float sw[64 * 8];
  __shared__ int ssrc[64];
  __shared__ float sm[8], sl[8], sadv[8], smean[8];
  __shared__ float sh2[256];
  int begin = row_ptr[n], end = row_ptr[n + 1];
  int degr = end - begin;
  if (lane < 8) { sm[lane] = -FLT_MAX; sl[lane] = 0.f; sadv[lane] = adv[(size_t)n * 8 + lane]; }
  float aedsum = 0.f;
  float4 acc = make_float4(0.f, 0.f, 0.f, 0.f);
  for (int cs = begin; cs < end; cs += 64) {
    int c = min(64, end - cs);
    __syncthreads();
    if (lane < c) ssrc[lane] = *(const int*)(rec + (size_t)(cs + lane) * 32);
    __syncthreads();
    for (int idx = lane; idx < c * 8; idx += 64) {
      int el = idx >> 3;
      float ae = __half2float(*(const __half*)(rec + (size_t)(cs + el) * 32 + 4 + hh * 2));
      aedsum += ae;
      float a = asv[(size_t)ssrc[el] * 8 + hh] + sadv[hh] + ae;
      a = a > 0.f ? a : 0.2f * a;
      sw[idx] = a;
    }
    __syncthreads();
    float mloc = -FLT_MAX;
    for (int el = sub; el < c; el += 8) mloc = fmaxf(mloc, sw[el * 8 + h]);
#pragma unroll
    for (int o = 1; o < 8; o <<= 1) mloc = fmaxf(mloc, __shfl_xor(mloc, o));
    float mold = sm[h];
    float mnew = fmaxf(mold, mloc);
    float scale = __expf(mold - mnew);
    float lloc = 0.f;
    for (int el = sub; el < c; el += 8) {
      float w = __expf(sw[el * 8 + h] - mnew);
      sw[el * 8 + h] = w;
      lloc += w;
    }
#pragma unroll
    for (int o = 1; o < 8; o <<= 1) lloc += __shfl_xor(lloc, o);
    __syncthreads();
    if (sub == 0) { sm[h] = mnew; sl[h] = sl[h] * scale + lloc; }
    acc.x *= scale; acc.y *= scale; acc.z *= scale; acc.w *= scale;
    for (int el = 0; el < c; el++) {
      float w = sw[el * 8 + h];
      ushort4 hv = *(const ushort4*)(h1b + (size_t)ssrc[el] * 256 + lane * 4);
      acc.x += w * bf2f(hv.x);
      acc.y += w * bf2f(hv.y);
      acc.z += w * bf2f(hv.z);
      acc.w += w * bf2f(hv.w);
    }
  }
  // per-head aed mean
  aedsum += __shfl_xor(aedsum, 8);
  aedsum += __shfl_xor(aedsum, 16);
  aedsum += __shfl_xor(aedsum, 32);
  float invd = 1.f / (float)(degr > 1 ? degr : 1);
  if (lane < 8) smean[lane] = aedsum * invd;
  __syncthreads();
  // merged self-loop step
  float a_self = asv[(size_t)n * 8 + h] + sadv[h] + smean[h];
  a_self = a_self > 0.f ? a_self : 0.2f * a_self;
  float mold = sm[h];
  float mnew = fmaxf(mold, a_self);
  float scale = __expf(mold - mnew);
  float w_self = __expf(a_self - mnew);
  float l_fin = sl[h] * scale + w_self;
  ushort4 hs = *(const ushort4*)(h1b + (size_t)n * 256 + lane * 4);
  acc.x = acc.x * scale + w_self * bf2f(hs.x);
  acc.y = acc.y * scale + w_self * bf2f(hs.y);
  acc.z = acc.z * scale + w_self * bf2f(hs.z);
  acc.w = acc.w * scale + w_self * bf2f(hs.w);
  float inv = 1.f / (l_fin + 1e-16f);
  float4 bv = *(const float4*)(b1 + lane * 4);
  float4 h2v;
  h2v.x = fmaxf(acc.x * inv + bv.x, 0.f);
  h2v.y = fmaxf(acc.y * inv + bv.y, 0.f);
  h2v.z = fmaxf(acc.z * inv + bv.z, 0.f);
  h2v.w = fmaxf(acc.w * inv + bv.w, 0.f);
  *(float4*)&sh2[lane * 4] = h2v;
  __syncthreads();
  // fused gemm2 (bf16 weights): g2[cc] = sum_k h2[k]*W2[k][cc]; halves split k.
  int half = lane >> 5, cc = lane & 31;
  const ushort* wp = W2B + (size_t)half * 32 * 128 + cc * 4;
  const float* hp2 = sh2 + half * 128;
  float part = 0.f;
#pragma unroll 8
  for (int g = 0; g < 32; g++) {
    ushort4 wv = *(const ushort4*)(wp + g * 128);
    float4 hv = *(const float4*)(hp2 + g * 4);
    part += bf2f(wv.x) * hv.x + bf2f(wv.y) * hv.y +
            bf2f(wv.z) * hv.z + bf2f(wv.w) * hv.w;
  }
  part += __shfl_xor(part, 32);
  float s1 = part * as2[cc];
  float s2 = part * ad2[cc];
#pragma unroll
  for (int o = 1; o < 32; o <<= 1) {
    s1 += __shfl_xor(s1, o);
    s2 += __shfl_xor(s2, o);
  }
  if (lane < 32) g2b[(size_t)n * 32 + cc] = f2bf(part);
  if (lane == 0) { asv2[n] = s1; adv2[n] = s2; }
}

// ---- conv2: ONE WAVE per node (r11 structure); g2 gathered as bf16.
__global__ __launch_bounds__(64) void k_conv2(
    const int* __restrict__ row_ptr, const char* __restrict__ rec,
    const float* __restrict__ asv2, const float* __restrict__ adv2,
    const ushort* __restrict__ g2b, const float* __restrict__ b2,
    float* __restrict__ out, int N) {
  int n = blockIdx.x;
  int lane = threadIdx.x;
  int sub = lane >> 3, q = lane & 7;
  __shared__ float sw[64];
  __shared__ int ssrc[64];
  int begin = row_ptr[n], end = row_ptr[n + 1];
  int degr = end - begin;
  float advn = adv2[n];
  float m = -FLT_MAX, l = 0.f, aedsum = 0.f;
  float4 acc = make_float4(0.f, 0.f, 0.f, 0.f);
  for (int cs = begin; cs < end; cs += 64) {
    int c = min(64, end - cs);
    __syncthreads();
    float a = -FLT_MAX;
    if (lane < c) {
      const char* rp = rec + (size_t)(cs + lane) * 32;
      int s = *(const int*)rp;
      ssrc[lane] = s;
      float ae = *(const float*)(rp + 20);
      aedsum += ae;
      a = asv2[s] + advn + ae;
      a = a > 0.f ? a : 0.2f * a;
    }
    float cm = a;
#pragma unroll
    for (int o = 1; o < 64; o <<= 1) cm = fmaxf(cm, __shfl_xor(cm, o));
    float nm = fmaxf(m, cm);
    float sc = __expf(m - nm);
    float w = (lane < c) ? __expf(a - nm) : 0.f;
    float cl = w;
#pragma unroll
    for (int o = 1; o < 64; o <<= 1) cl += __shfl_xor(cl, o);
    l = l * sc + cl;
    m = nm;
    sw[lane] = w;
    __syncthreads();
    acc.x *= sc; acc.y *= sc; acc.z *= sc; acc.w *= sc;
    for (int el = sub; el < c; el += 8) {
      float w2 = sw[el];
      ushort4 gv = *(const ushort4*)(g2b + (size_t)ssrc[el] * 32 + q * 4);
      acc.x += w2 * bf2f(gv.x);
      acc.y += w2 * bf2f(gv.y);
      acc.z += w2 * bf2f(gv.z);
      acc.w += w2 * bf2f(gv.w);
    }
  }
  // self-loop merge
#pragma unroll
  for (int o = 1; o < 64; o <<= 1) aedsum += __shfl_xor(aedsum, o);
  float invd = 1.f / (float)(degr > 1 ? degr : 1);
  float a_self = asv2[n] + advn + aedsum * invd;
  a_self = a_self > 0.f ? a_self : 0.2f * a_self;
  float nm = fmaxf(m, a_self);
  float sc = __expf(m - nm);
  float w_self = __expf(a_self - nm);
  l = l * sc + w_self;
  acc.x *= sc; acc.y *= sc; acc.z *= sc; acc.w *= sc;
  if (sub == 0) {
    ushort4 gv = *(const ushort4*)(g2b + (size_t)n * 32 + q * 4);
    acc.x += w_self * bf2f(gv.x);
    acc.y += w_self * bf2f(gv.y);
    acc.z += w_self * bf2f(gv.z);
    acc.w += w_self * bf2f(gv.w);
  }
#pragma unroll
  for (int o = 8; o < 64; o <<= 1) {
    acc.x += __shfl_xor(acc.x, o);
    acc.y += __shfl_xor(acc.y, o);
    acc.z += __shfl_xor(acc.z, o);
    acc.w += __shfl_xor(acc.w, o);
  }
  if (lane < 8) {
    float inv = 1.f / (l + 1e-16f);
    float4 bv = *(const float4*)(b2 + lane * 4);
    float4 o4;
    o4.x = acc.x * inv + bv.x;
    o4.y = acc.y * inv + bv.y;
    o4.z = acc.z * inv + bv.z;
    o4.w = acc.w * inv + bv.w;
    *(float4*)(out + (size_t)n * 32 + lane * 4) = o4;
  }
}

// ---------------------------------------------------------------- launch
extern "C" void kernel_launch(void* const* d_in, const int* in_sizes, int n_in,
                              void* d_out, int out_size, void* d_ws, size_t ws_size,
                              hipStream_t stream) {
  (void)n_in; (void)out_size; (void)ws_size;
  const float* x   = (const float*)d_in[0];
  const int*   ei  = (const int*)d_in[1];
  const float* ea  = (const float*)d_in[2];
  const float* Wse = (const float*)d_in[3];
  const float* bse = (const float*)d_in[4];
  const float* W1  = (const float*)d_in[5];
  const float* as1 = (const float*)d_in[6];
  const float* ad1 = (const float*)d_in[7];
  const float* We1 = (const float*)d_in[8];
  const float* ae1 = (const float*)d_in[9];
  const float* b1  = (const float*)d_in[10];
  const float* W2  = (const float*)d_in[11];
  const float* as2 = (const float*)d_in[12];
  const float* ad2 = (const float*)d_in[13];
  const float* We2 = (const float*)d_in[14];
  const float* ae2 = (const float*)d_in[15];
  const float* b2  = (const float*)d_in[16];
  const int N = in_sizes[0] / 256;
  const int E = in_sizes[1] / 2;
  const int* src = ei;
  const int* dst = ei + E;

  char* base = (char*)d_ws;
  size_t off = 0;
  auto alloc = [&](size_t bytes) -> char* {
    off = (off + 255) & ~(size_t)255;
    char* p = base + off;
    off += bytes;
    return p;
  };
  int*   deg      = (int*)alloc((size_t)N * 4);
  int*   cursor   = (int*)alloc((size_t)N * 4);
  int* row_ptr    = (int*)alloc((size_t)(N + 1) * 4);
  char* rec       = alloc((size_t)E * 32);
  ushort* W1T     = (ushort*)alloc((size_t)256 * 256 * 2);
  ushort* W2B     = (ushort*)alloc((size_t)256 * 32 * 2);
  ushort* h1b     = (ushort*)alloc((size_t)N * 256 * 2);
  float* asv1     = (float*)alloc((size_t)N * 8 * 4);
  float* adv1     = (float*)alloc((size_t)N * 8 * 4);
  ushort* g2b     = (ushort*)alloc((size_t)N * 32 * 2);
  float* asv2     = (float*)alloc((size_t)N * 4);
  float* adv2     = (float*)alloc((size_t)N * 4);
  float* M1       = (float*)alloc(64 * 4);
  float* m2       = (float*)alloc(8 * 4);

  const int DB = (E + 255) / 256;
  const int GB = (N + 63) / 64;
  hipMemsetAsync(deg, 0, (size_t)N * 4, stream);
  k_pre<<<DB + 65, 256, 0, stream>>>(dst, W1, We1, ae1, We2, ae2, W2,
                                     deg, W1T, M1, m2, W2B, E, DB);
  k_scan<<<1, 1024, 0, stream>>>(deg, row_ptr, cursor, N);
  k_mega1<<<GB + DB, 256, 0, stream>>>(x, W1T, as1, ad1, h1b, asv1, adv1, N,
                                       src, dst, ea, Wse, bse, M1, m2, row_ptr,
                                       cursor, rec, E, GB);
  k_conv1<<<N, 64, 0, stream>>>(row_ptr, rec, asv1, adv1, h1b, b1,
                                W2B, as2, ad2, g2b, asv2, adv2, N);
  k_conv2<<<N, 64, 0, stream>>>(row_ptr, rec, asv2, adv2, g2b, b2, (float*)d_out, N);
}